// Round 1
// baseline (1654.654 us; speedup 1.0000x reference)
//
#include <hip/hip_runtime.h>
#include <hip/hip_bf16.h>

// h_out[v] = sum over edges (u->v) of features[u]
// features: [N_NODES, 5] float32
// src, dst: [N_EDGES] int32 (JAX x64 disabled -> int64 request degrades to int32;
//                            harness convention: integer -> const int*)
// out: [N_NODES, 5] float32

#define DIM_FEAT 5

__global__ void scatter_add_kernel(const float* __restrict__ features,
                                   const int* __restrict__ src,
                                   const int* __restrict__ dst,
                                   float* __restrict__ out,
                                   int n_edges) {
    int idx = blockIdx.x * blockDim.x + threadIdx.x;
    int stride = gridDim.x * blockDim.x;
    for (int e = idx; e < n_edges; e += stride) {
        int u = src[e];
        int v = dst[e];
        const float* frow = features + (long long)u * DIM_FEAT;
        float* orow = out + (long long)v * DIM_FEAT;
#pragma unroll
        for (int f = 0; f < DIM_FEAT; ++f) {
            atomicAdd(&orow[f], frow[f]);
        }
    }
}

extern "C" void kernel_launch(void* const* d_in, const int* in_sizes, int n_in,
                              void* d_out, int out_size, void* d_ws, size_t ws_size,
                              hipStream_t stream) {
    const float* features = (const float*)d_in[0];
    const int*   src      = (const int*)d_in[1];
    const int*   dst      = (const int*)d_in[2];
    float* out = (float*)d_out;

    int n_edges = in_sizes[1];

    // Harness poisons d_out with 0xAA before every launch; we accumulate, so zero it.
    hipMemsetAsync(d_out, 0, (size_t)out_size * sizeof(float), stream);

    int block = 256;
    int grid = (n_edges + block - 1) / block;
    if (grid > 65535) grid = 65535;  // grid-stride handles the rest
    scatter_add_kernel<<<grid, block, 0, stream>>>(features, src, dst, out, n_edges);
}

// Round 2
// 626.539 us; speedup vs baseline: 2.6409x; 2.6409x over previous
//
#include <hip/hip_runtime.h>
#include <hip/hip_bf16.h>

// h_out[v] = sum over edges (u->v) of features[u]
// features: [100000, 5] f32; src,dst: [6400000] int32; out: [100000,5] f32

#define N_NODES  100000
#define DIM_FEAT 5
#define NOUT     (N_NODES * DIM_FEAT)   // 500000 floats
#define S_SLICES 32
#define NPS      (N_NODES / S_SLICES)   // 3125 nodes per slice
#define BLOCK    256

// Block (s,c): accumulate slice s over edge-chunk c into LDS, flush to replica c.
__global__ __launch_bounds__(BLOCK) void slice_scan_kernel(
    const float* __restrict__ features,
    const int*   __restrict__ src,
    const int*   __restrict__ dst,
    float*       __restrict__ rep,     // [n_chunks][NOUT]
    int n_edges, int n_chunks)
{
    __shared__ float acc[NPS * DIM_FEAT];  // 62500 B
    for (int i = threadIdx.x; i < NPS * DIM_FEAT; i += BLOCK) acc[i] = 0.0f;
    __syncthreads();

    // c = bid % n_chunks: with n_chunks=16, the 32 blocks sharing chunk c land on
    // the same XCD under the bid%8 round-robin heuristic -> chunk stays in that L2.
    int c = blockIdx.x % n_chunks;
    int s = blockIdx.x / n_chunks;
    int lo = s * NPS;

    int chunk = n_edges / n_chunks;            // divisible by 4 for pow2 n_chunks
    long long e0 = (long long)c * chunk;
    const int4* dst4 = (const int4*)(dst + e0);
    int n4 = chunk >> 2;

    for (int i = threadIdx.x; i < n4; i += BLOCK) {
        int4 d = dst4[i];
        long long ebase = e0 + ((long long)i << 2);
        int vs[4] = {d.x, d.y, d.z, d.w};
#pragma unroll
        for (int j = 0; j < 4; ++j) {
            unsigned vl = (unsigned)(vs[j] - lo);
            if (vl < (unsigned)NPS) {
                int u = src[ebase + j];
                const float* f = features + (long long)u * DIM_FEAT;
                float* a = acc + vl * DIM_FEAT;
                atomicAdd(&a[0], f[0]);
                atomicAdd(&a[1], f[1]);
                atomicAdd(&a[2], f[2]);
                atomicAdd(&a[3], f[3]);
                atomicAdd(&a[4], f[4]);
            }
        }
    }
    __syncthreads();

    // Plain coalesced stores: replica c slice s is owned exclusively by this block.
    float* o = rep + (long long)c * NOUT + (long long)lo * DIM_FEAT;
    for (int i = threadIdx.x; i < NPS * DIM_FEAT; i += BLOCK) o[i] = acc[i];
}

__global__ void merge_kernel(const float* __restrict__ rep,
                             float* __restrict__ out, int n_chunks) {
    int i = blockIdx.x * blockDim.x + threadIdx.x;
    if (i < NOUT / 4) {
        float4 sum = make_float4(0.f, 0.f, 0.f, 0.f);
        for (int c = 0; c < n_chunks; ++c) {
            float4 v = ((const float4*)(rep + (long long)c * NOUT))[i];
            sum.x += v.x; sum.y += v.y; sum.z += v.z; sum.w += v.w;
        }
        ((float4*)out)[i] = sum;
    }
}

// Fallback (ws too small): round-1 direct-atomic version.
__global__ void scatter_add_fallback(const float* __restrict__ features,
                                     const int* __restrict__ src,
                                     const int* __restrict__ dst,
                                     float* __restrict__ out, int n_edges) {
    int idx = blockIdx.x * blockDim.x + threadIdx.x;
    int stride = gridDim.x * blockDim.x;
    for (int e = idx; e < n_edges; e += stride) {
        int u = src[e], v = dst[e];
        const float* f = features + (long long)u * DIM_FEAT;
        float* o = out + (long long)v * DIM_FEAT;
#pragma unroll
        for (int k = 0; k < DIM_FEAT; ++k) atomicAdd(&o[k], f[k]);
    }
}

extern "C" void kernel_launch(void* const* d_in, const int* in_sizes, int n_in,
                              void* d_out, int out_size, void* d_ws, size_t ws_size,
                              hipStream_t stream) {
    const float* features = (const float*)d_in[0];
    const int*   src      = (const int*)d_in[1];
    const int*   dst      = (const int*)d_in[2];
    float* out = (float*)d_out;
    int n_edges = in_sizes[1];

    size_t rep_bytes = (size_t)NOUT * sizeof(float);  // 2 MB per replica
    int C = 16;
    while (C > 1 && (size_t)C * rep_bytes > ws_size) C >>= 1;

    if ((size_t)C * rep_bytes <= ws_size) {
        slice_scan_kernel<<<S_SLICES * C, BLOCK, 0, stream>>>(
            features, src, dst, (float*)d_ws, n_edges, C);
        int mgrid = (NOUT / 4 + BLOCK - 1) / BLOCK;
        merge_kernel<<<mgrid, BLOCK, 0, stream>>>((const float*)d_ws, out, C);
    } else {
        hipMemsetAsync(d_out, 0, (size_t)out_size * sizeof(float), stream);
        int grid = (n_edges + BLOCK - 1) / BLOCK;
        if (grid > 65535) grid = 65535;
        scatter_add_fallback<<<grid, BLOCK, 0, stream>>>(features, src, dst, out, n_edges);
    }
}

// Round 3
// 387.659 us; speedup vs baseline: 4.2683x; 1.6162x over previous
//
#include <hip/hip_runtime.h>
#include <hip/hip_bf16.h>

// h_out[v] = sum over edges (u->v) of features[u]
// Strategy: counting-sort edges by dst-bucket (128 nodes/bucket), then one
// block per bucket accumulates in a tiny LDS tile and stores exclusively.

#define NN     100000
#define FD     5
#define NOUTT  (NN * FD)      // 500000
#define NPS    128            // nodes per bucket (pow2)
#define NPS_SH 7
#define NB     782            // ceil(NN / NPS)
#define NBP    1024           // padded bucket count for scan
#define NSB    256            // scatter blocks
#define BLK    256

// K1: pad feature rows 5 f32 -> 8 f32 (32 B, never straddles a 64 B line)
__global__ __launch_bounds__(BLK) void k1_pad(const float* __restrict__ f,
                                              float4* __restrict__ fp) {
    int i = blockIdx.x * BLK + threadIdx.x;
    if (i < NN) {
        const float* r = f + (long long)i * FD;
        fp[2 * i]     = make_float4(r[0], r[1], r[2], r[3]);
        fp[2 * i + 1] = make_float4(r[4], 0.f, 0.f, 0.f);
    }
}

// K2: per-scatter-block bucket histogram
__global__ __launch_bounds__(BLK) void k2_hist(const int* __restrict__ dst,
                                               int* __restrict__ blk_hist, int chunk) {
    __shared__ int h[NB];
    for (int b = threadIdx.x; b < NB; b += BLK) h[b] = 0;
    __syncthreads();
    long long e0 = (long long)blockIdx.x * chunk;
    const int4* d4 = (const int4*)(dst + e0);
    int n4 = chunk >> 2;
    for (int i = threadIdx.x; i < n4; i += BLK) {
        int4 d = d4[i];
        atomicAdd(&h[d.x >> NPS_SH], 1);
        atomicAdd(&h[d.y >> NPS_SH], 1);
        atomicAdd(&h[d.z >> NPS_SH], 1);
        atomicAdd(&h[d.w >> NPS_SH], 1);
    }
    __syncthreads();
    for (int b = threadIdx.x; b < NB; b += BLK)
        blk_hist[b * NSB + blockIdx.x] = h[b];
}

// K3: per bucket, exclusive scan across the 256 scatter blocks (in place)
__global__ __launch_bounds__(BLK) void k3_scanblk(int* __restrict__ blk_hist,
                                                  int* __restrict__ btot) {
    __shared__ int s[BLK];
    int b = blockIdx.x, t = threadIdx.x;
    int x = blk_hist[b * NSB + t];
    s[t] = x;
    __syncthreads();
    for (int off = 1; off < BLK; off <<= 1) {
        int v = (t >= off) ? s[t - off] : 0;
        __syncthreads();
        s[t] += v;
        __syncthreads();
    }
    blk_hist[b * NSB + t] = s[t] - x;          // exclusive prefix
    if (t == BLK - 1) btot[b] = s[t];          // bucket total
}

// K4: exclusive scan of bucket totals -> bucket bases (1 block)
__global__ __launch_bounds__(BLK) void k4_scanbkt(const int* __restrict__ btot,
                                                  int* __restrict__ bbase) {
    __shared__ int s[BLK];
    int t = threadIdx.x;
    int v[4], sum = 0;
#pragma unroll
    for (int k = 0; k < 4; ++k) {
        int i = 4 * t + k;
        v[k] = (i < NB) ? btot[i] : 0;
        sum += v[k];
    }
    s[t] = sum;
    __syncthreads();
    for (int off = 1; off < BLK; off <<= 1) {
        int u = (t >= off) ? s[t - off] : 0;
        __syncthreads();
        s[t] += u;
        __syncthreads();
    }
    int run = s[t] - sum;
#pragma unroll
    for (int k = 0; k < 4; ++k) { bbase[4 * t + k] = run; run += v[k]; }
}

// K5: scatter packed (src<<7 | local_dst) into bucket-sorted order.
// LDS cursors are pre-offset with the deterministic global base, so one LDS
// atomicAdd yields the final global slot — no global atomics at all.
__global__ __launch_bounds__(BLK) void k5_scatter(const int* __restrict__ src,
                                                  const int* __restrict__ dst,
                                                  const int* __restrict__ blk_hist,
                                                  const int* __restrict__ bbase,
                                                  int* __restrict__ bdata, int chunk) {
    __shared__ int cur[NB];
    int blk = blockIdx.x;
    for (int b = threadIdx.x; b < NB; b += BLK)
        cur[b] = bbase[b] + blk_hist[b * NSB + blk];
    __syncthreads();
    long long e0 = (long long)blk * chunk;
    const int4* d4 = (const int4*)(dst + e0);
    const int4* s4 = (const int4*)(src + e0);
    int n4 = chunk >> 2;
    for (int i = threadIdx.x; i < n4; i += BLK) {
        int4 d = d4[i];
        int4 s = s4[i];
        int vv[4] = {d.x, d.y, d.z, d.w};
        int uu[4] = {s.x, s.y, s.z, s.w};
#pragma unroll
        for (int j = 0; j < 4; ++j) {
            int b = vv[j] >> NPS_SH;
            int off = atomicAdd(&cur[b], 1);
            bdata[off] = (uu[j] << NPS_SH) | (vv[j] & (NPS - 1));
        }
    }
}

// K6: one block per bucket — gather features, LDS-accumulate, exclusive store.
__global__ __launch_bounds__(BLK) void k6_gather(const int* __restrict__ bdata,
                                                 const float4* __restrict__ fp,
                                                 const int* __restrict__ bbase,
                                                 const int* __restrict__ btot,
                                                 float* __restrict__ out) {
    __shared__ float acc[NPS * FD];   // 2.5 KB
    for (int j = threadIdx.x; j < NPS * FD; j += BLK) acc[j] = 0.f;
    __syncthreads();
    int b = blockIdx.x;
    int base = bbase[b];
    int n = btot[b];
    int t = threadIdx.x;
    int i = t;
    // 4-way unrolled: 4 independent gather chains in flight
    for (; i + 3 * BLK < n; i += 4 * BLK) {
        int w0 = bdata[base + i];
        int w1 = bdata[base + i + BLK];
        int w2 = bdata[base + i + 2 * BLK];
        int w3 = bdata[base + i + 3 * BLK];
        int u0 = w0 >> NPS_SH, l0 = w0 & (NPS - 1);
        int u1 = w1 >> NPS_SH, l1 = w1 & (NPS - 1);
        int u2 = w2 >> NPS_SH, l2 = w2 & (NPS - 1);
        int u3 = w3 >> NPS_SH, l3 = w3 & (NPS - 1);
        float4 a0 = fp[2 * u0], c0 = fp[2 * u0 + 1];
        float4 a1 = fp[2 * u1], c1 = fp[2 * u1 + 1];
        float4 a2 = fp[2 * u2], c2 = fp[2 * u2 + 1];
        float4 a3 = fp[2 * u3], c3 = fp[2 * u3 + 1];
        atomicAdd(&acc[l0 * FD + 0], a0.x); atomicAdd(&acc[l0 * FD + 1], a0.y);
        atomicAdd(&acc[l0 * FD + 2], a0.z); atomicAdd(&acc[l0 * FD + 3], a0.w);
        atomicAdd(&acc[l0 * FD + 4], c0.x);
        atomicAdd(&acc[l1 * FD + 0], a1.x); atomicAdd(&acc[l1 * FD + 1], a1.y);
        atomicAdd(&acc[l1 * FD + 2], a1.z); atomicAdd(&acc[l1 * FD + 3], a1.w);
        atomicAdd(&acc[l1 * FD + 4], c1.x);
        atomicAdd(&acc[l2 * FD + 0], a2.x); atomicAdd(&acc[l2 * FD + 1], a2.y);
        atomicAdd(&acc[l2 * FD + 2], a2.z); atomicAdd(&acc[l2 * FD + 3], a2.w);
        atomicAdd(&acc[l2 * FD + 4], c2.x);
        atomicAdd(&acc[l3 * FD + 0], a3.x); atomicAdd(&acc[l3 * FD + 1], a3.y);
        atomicAdd(&acc[l3 * FD + 2], a3.z); atomicAdd(&acc[l3 * FD + 3], a3.w);
        atomicAdd(&acc[l3 * FD + 4], c3.x);
    }
    for (; i < n; i += BLK) {
        int w = bdata[base + i];
        int u = w >> NPS_SH, l = w & (NPS - 1);
        float4 a = fp[2 * u], c = fp[2 * u + 1];
        atomicAdd(&acc[l * FD + 0], a.x); atomicAdd(&acc[l * FD + 1], a.y);
        atomicAdd(&acc[l * FD + 2], a.z); atomicAdd(&acc[l * FD + 3], a.w);
        atomicAdd(&acc[l * FD + 4], c.x);
    }
    __syncthreads();
    int node0 = b * NPS;
    int nn = NN - node0; if (nn > NPS) nn = NPS;
    int nfl = nn * FD;
    float* o = out + (long long)node0 * FD;
    for (int j = t; j < nfl; j += BLK) o[j] = acc[j];
}

// Fallback: direct global atomics (round-1 version)
__global__ void scatter_add_fallback(const float* __restrict__ features,
                                     const int* __restrict__ src,
                                     const int* __restrict__ dst,
                                     float* __restrict__ out, int n_edges) {
    int idx = blockIdx.x * blockDim.x + threadIdx.x;
    int stride = gridDim.x * blockDim.x;
    for (int e = idx; e < n_edges; e += stride) {
        int u = src[e], v = dst[e];
        const float* f = features + (long long)u * FD;
        float* o = out + (long long)v * FD;
#pragma unroll
        for (int k = 0; k < FD; ++k) atomicAdd(&o[k], f[k]);
    }
}

extern "C" void kernel_launch(void* const* d_in, const int* in_sizes, int n_in,
                              void* d_out, int out_size, void* d_ws, size_t ws_size,
                              hipStream_t stream) {
    const float* features = (const float*)d_in[0];
    const int*   src      = (const int*)d_in[1];
    const int*   dst      = (const int*)d_in[2];
    float* out = (float*)d_out;
    int n_edges = in_sizes[1];

    // ws carve (all offsets 16 B aligned given n_edges % 1024 == 0)
    size_t o_bd = 0;
    size_t o_fp = o_bd + (size_t)n_edges * 4;              // bucket_data
    size_t o_bh = o_fp + (size_t)NN * 2 * sizeof(float4);  // padded features
    size_t o_bb = o_bh + (size_t)NB * NSB * 4;             // blk_hist
    size_t o_bt = o_bb + (size_t)NBP * 4;                  // bucket_base
    size_t need = o_bt + (size_t)NBP * 4;                  // bucket_total

    bool fast = (out_size == NOUTT) && (in_sizes[0] == NOUTT) &&
                (n_edges % (NSB * 4) == 0) && (need <= ws_size);

    if (fast) {
        char* w = (char*)d_ws;
        int*    bdata = (int*)(w + o_bd);
        float4* fpad  = (float4*)(w + o_fp);
        int*    bhist = (int*)(w + o_bh);
        int*    bbase = (int*)(w + o_bb);
        int*    btot  = (int*)(w + o_bt);
        int chunk = n_edges / NSB;
        k1_pad   <<<(NN + BLK - 1) / BLK, BLK, 0, stream>>>(features, fpad);
        k2_hist  <<<NSB, BLK, 0, stream>>>(dst, bhist, chunk);
        k3_scanblk<<<NB, BLK, 0, stream>>>(bhist, btot);
        k4_scanbkt<<<1,  BLK, 0, stream>>>(btot, bbase);
        k5_scatter<<<NSB, BLK, 0, stream>>>(src, dst, bhist, bbase, bdata, chunk);
        k6_gather <<<NB,  BLK, 0, stream>>>(bdata, fpad, bbase, btot, out);
    } else {
        hipMemsetAsync(d_out, 0, (size_t)out_size * sizeof(float), stream);
        int grid = (n_edges + BLK - 1) / BLK;
        if (grid > 65535) grid = 65535;
        scatter_add_fallback<<<grid, BLK, 0, stream>>>(features, src, dst, out, n_edges);
    }
}